// Round 1
// baseline (591.731 us; speedup 1.0000x reference)
//
#include <hip/hip_runtime.h>
#include <stdint.h>

typedef unsigned short u16;
typedef __attribute__((ext_vector_type(8))) __bf16 bf16x8;
typedef __attribute__((ext_vector_type(4))) float f32x4;

#define B_TOTAL 65536
#define KPAD1   1440   // 1424 padded to multiple of 32

__device__ __forceinline__ u16 f2bf(float f) {
  union { float f; uint32_t u; } v; v.f = f;
  uint32_t r = v.u + 0x7fffu + ((v.u >> 16) & 1u);
  return (u16)(r >> 16);
}
__device__ __forceinline__ float bf2f(u16 h) {
  union { uint32_t u; float f; } v; v.u = ((uint32_t)h) << 16;
  return v.f;
}

__device__ __forceinline__ void gload16(const void* g, void* lds) {
  __builtin_amdgcn_global_load_lds(
      (const __attribute__((address_space(1))) uint32_t*)g,
      (__attribute__((address_space(3))) uint32_t*)lds, 16, 0, 0);
}

// ---------------- weight prep: f32 [K][N] -> bf16 [N][Kpad] (transposed, zero-padded K)
__global__ void wprep_kernel(const float* __restrict__ W, u16* __restrict__ Wt,
                             int K, int N, int Kpad) {
  int o = blockIdx.x * 256 + threadIdx.x;
  if (o >= N * Kpad) return;
  int k = o % Kpad;
  int n = o / Kpad;
  float v = (k < K) ? W[(size_t)k * N + n] : 0.0f;
  Wt[o] = f2bf(v);
}

// ---------------- gather + concat -> X bf16 [Bc][1440]
struct GatherArgs {
  const int*   idx[15];
  const float* E[15];
  const int*   idx_u;
  const float* E_u;
};

// feature dims / concat offsets (userids: off 1312, dim 112)
constexpr int FDIM[15] = {128,128,128,16,16,96,144,64,80,64,48,144,96,16,144};
constexpr int FOFF[15] = {0,128,256,384,400,416,512,656,720,800,864,912,1056,1152,1168};

__global__ void gather_kernel(GatherArgs p, u16* __restrict__ X, int row_base) {
  const int lane = threadIdx.x & 63;
  const int row  = blockIdx.x * 4 + (threadIdx.x >> 6);
  const int grow = row_base + row;
  u16* xrow = X + (size_t)row * KPAD1;

#pragma unroll
  for (int f = 0; f < 15; ++f) {
    const int id = p.idx[f][grow];
    const float* src = p.E[f] + (size_t)id * FDIM[f];
    const int ng = FDIM[f] / 4;
    if (lane < ng) {
      const float4 v = *reinterpret_cast<const float4*>(src + lane * 4);
      ushort4 o;
      o.x = f2bf(v.x); o.y = f2bf(v.y); o.z = f2bf(v.z); o.w = f2bf(v.w);
      *reinterpret_cast<ushort4*>(xrow + FOFF[f] + lane * 4) = o;
    }
  }
  // userids mean-pool over 50, dim 112: lanes 0..55 take 2 cols each
  const int* iu = p.idx_u + (size_t)grow * 50;
  if (lane < 56) {
    float sx = 0.f, sy = 0.f;
    for (int j = 0; j < 50; ++j) {
      const int id = iu[j];
      const float2 v = *reinterpret_cast<const float2*>(p.E_u + (size_t)id * 112 + lane * 2);
      sx += v.x; sy += v.y;
    }
    const float inv = 1.0f / 50.0f;
    ushort2 o; o.x = f2bf(sx * inv); o.y = f2bf(sy * inv);
    *reinterpret_cast<ushort2*>(xrow + 1312 + lane * 2) = o;
  } else if (lane < 60) {
    // zero pad cols 1424..1439
    ushort4 z; z.x = 0; z.y = 0; z.z = 0; z.w = 0;
    *reinterpret_cast<ushort4*>(xrow + 1424 + (lane - 56) * 4) = z;
  }
}

// ---------------- bf16 MFMA GEMM: C[M][N] = relu(A[M][K] * Wt[N][K]^T + bias), bf16 out
#define BM 128
#define BN 128
#define BK 32

__global__ __launch_bounds__(256, 2) void gemm_bias_relu(
    const u16* __restrict__ A, const u16* __restrict__ Wt,
    const float* __restrict__ bias, u16* __restrict__ C,
    int M, int N, int K) {
  __shared__ __align__(16) u16 Asm[BM * BK];
  __shared__ __align__(16) u16 Bsm[BN * BK];
  const int tid  = threadIdx.x;
  const int wave = tid >> 6;
  const int lane = tid & 63;
  const int row0 = blockIdx.x * BM;
  const int col0 = blockIdx.y * BN;
  const int wm = (wave >> 1) * 64;
  const int wn = (wave & 1) * 64;
  const int fr = lane & 15;   // fragment row/col
  const int kg = lane >> 4;   // k-group

  f32x4 acc[4][4];
#pragma unroll
  for (int m = 0; m < 4; ++m)
#pragma unroll
    for (int n = 0; n < 4; ++n)
      acc[m][n] = f32x4{0.f, 0.f, 0.f, 0.f};

  const int srow  = lane >> 2;        // 0..15
  const int skcol = (lane & 3) * 8;   // k elem offset for this lane's 16B

  for (int k0 = 0; k0 < K; k0 += BK) {
#pragma unroll
    for (int i = 0; i < 2; ++i) {
      const int sec = wave * 32 + i * 16;            // 16-row section
      const u16* ga = A  + (size_t)(row0 + sec + srow) * K + k0 + skcol;
      gload16(ga, &Asm[(size_t)sec * BK]);
      const u16* gb = Wt + (size_t)(col0 + sec + srow) * K + k0 + skcol;
      gload16(gb, &Bsm[(size_t)sec * BK]);
    }
    __syncthreads();

    bf16x8 af[4], bg[4];
#pragma unroll
    for (int m = 0; m < 4; ++m)
      af[m] = *reinterpret_cast<const bf16x8*>(&Asm[(wm + m * 16 + fr) * BK + kg * 8]);
#pragma unroll
    for (int n = 0; n < 4; ++n)
      bg[n] = *reinterpret_cast<const bf16x8*>(&Bsm[(wn + n * 16 + fr) * BK + kg * 8]);
#pragma unroll
    for (int m = 0; m < 4; ++m)
#pragma unroll
      for (int n = 0; n < 4; ++n)
        acc[m][n] = __builtin_amdgcn_mfma_f32_16x16x32_bf16(af[m], bg[n], acc[m][n], 0, 0, 0);
    __syncthreads();
  }

#pragma unroll
  for (int n = 0; n < 4; ++n) {
    const int gcol = col0 + wn + n * 16 + fr;
    const float bv = bias[gcol];
#pragma unroll
    for (int m = 0; m < 4; ++m) {
      const int grow0 = row0 + wm + m * 16 + kg * 4;
#pragma unroll
      for (int j = 0; j < 4; ++j) {
        float v = acc[m][n][j] + bv;
        v = fmaxf(v, 0.f);
        C[(size_t)(grow0 + j) * N + gcol] = f2bf(v);
      }
    }
  }
}

// ---------------- final: h3[Bc][256] -> relu(h3*W4+b4) -> softmax(2) -> f32 out
__global__ void final_kernel(const u16* __restrict__ H3, const float* __restrict__ W4,
                             const float* __restrict__ b4, float* __restrict__ out, int M) {
  const int lane = threadIdx.x & 63;
  const int row  = blockIdx.x * 4 + (threadIdx.x >> 6);
  const ushort4 h = *reinterpret_cast<const ushort4*>(H3 + (size_t)row * 256 + lane * 4);
  const float x0 = bf2f(h.x), x1 = bf2f(h.y), x2 = bf2f(h.z), x3 = bf2f(h.w);
  const float2 w0 = *reinterpret_cast<const float2*>(W4 + (size_t)(lane * 4 + 0) * 2);
  const float2 w1 = *reinterpret_cast<const float2*>(W4 + (size_t)(lane * 4 + 1) * 2);
  const float2 w2 = *reinterpret_cast<const float2*>(W4 + (size_t)(lane * 4 + 2) * 2);
  const float2 w3 = *reinterpret_cast<const float2*>(W4 + (size_t)(lane * 4 + 3) * 2);
  float s0 = x0 * w0.x + x1 * w1.x + x2 * w2.x + x3 * w3.x;
  float s1 = x0 * w0.y + x1 * w1.y + x2 * w2.y + x3 * w3.y;
#pragma unroll
  for (int off = 32; off > 0; off >>= 1) {
    s0 += __shfl_xor(s0, off);
    s1 += __shfl_xor(s1, off);
  }
  if (lane == 0) {
    float z0 = fmaxf(s0 + b4[0], 0.f);
    float z1 = fmaxf(s1 + b4[1], 0.f);
    float mx = fmaxf(z0, z1);
    float e0 = __expf(z0 - mx), e1 = __expf(z1 - mx);
    float inv = 1.0f / (e0 + e1);
    out[(size_t)row * 2]     = e0 * inv;
    out[(size_t)row * 2 + 1] = e1 * inv;
  }
}

// ---------------- host side
extern "C" void kernel_launch(void* const* d_in, const int* in_sizes, int n_in,
                              void* d_out, int out_size, void* d_ws, size_t ws_size,
                              hipStream_t stream) {
  const float* W1 = (const float*)d_in[32];
  const float* b1 = (const float*)d_in[33];
  const float* W2 = (const float*)d_in[34];
  const float* b2 = (const float*)d_in[35];
  const float* W3 = (const float*)d_in[36];
  const float* b3 = (const float*)d_in[37];
  const float* W4 = (const float*)d_in[38];
  const float* b4 = (const float*)d_in[39];

  char* ws = (char*)d_ws;
  size_t off = 0;
  auto alloc = [&](size_t bytes) -> void* {
    void* p = ws + off;
    off += (bytes + 255) & ~(size_t)255;
    return p;
  };

  u16* W1t = (u16*)alloc((size_t)1024 * KPAD1 * 2);
  u16* W2t = (u16*)alloc((size_t)512 * 1024 * 2);
  u16* W3t = (u16*)alloc((size_t)256 * 512 * 2);
  const size_t fixed = off;

  // pick the largest chunk that fits the workspace
  int nc = 64;
  const int cands[7] = {1, 2, 4, 8, 16, 32, 64};
  for (int ci = 0; ci < 7; ++ci) {
    size_t Bc = (size_t)B_TOTAL / cands[ci];
    size_t need = fixed + Bc * (KPAD1 + 1024 + 512 + 256) * 2 + 4096;
    if (need <= ws_size) { nc = cands[ci]; break; }
  }
  const int Bc = B_TOTAL / nc;

  u16* X  = (u16*)alloc((size_t)Bc * KPAD1 * 2);
  u16* H1 = (u16*)alloc((size_t)Bc * 1024 * 2);
  u16* H2 = (u16*)alloc((size_t)Bc * 512 * 2);
  u16* H3 = (u16*)alloc((size_t)Bc * 256 * 2);

  // weight prep (once per launch)
  wprep_kernel<<<(1024 * KPAD1 + 255) / 256, 256, 0, stream>>>(W1, W1t, 1424, 1024, KPAD1);
  wprep_kernel<<<(512 * 1024 + 255) / 256, 256, 0, stream>>>(W2, W2t, 1024, 512, 1024);
  wprep_kernel<<<(256 * 512 + 255) / 256, 256, 0, stream>>>(W3, W3t, 512, 256, 512);

  GatherArgs ga;
  for (int f = 0; f < 15; ++f) {
    ga.idx[f] = (const int*)d_in[2 * f];
    ga.E[f]   = (const float*)d_in[2 * f + 1];
  }
  ga.idx_u = (const int*)d_in[30];
  ga.E_u   = (const float*)d_in[31];

  for (int c = 0; c < nc; ++c) {
    gather_kernel<<<Bc / 4, 256, 0, stream>>>(ga, X, c * Bc);
    gemm_bias_relu<<<dim3(Bc / BM, 1024 / BN), 256, 0, stream>>>(X, W1t, b1, H1, Bc, 1024, KPAD1);
    gemm_bias_relu<<<dim3(Bc / BM, 512 / BN), 256, 0, stream>>>(H1, W2t, b2, H2, Bc, 512, 1024);
    gemm_bias_relu<<<dim3(Bc / BM, 256 / BN), 256, 0, stream>>>(H2, W3t, b3, H3, Bc, 256, 512);
    final_kernel<<<Bc / 4, 256, 0, stream>>>(H3, W4, b4, (float*)d_out + (size_t)c * Bc * 2, Bc);
  }
}

// Round 6
// 554.949 us; speedup vs baseline: 1.0663x; 1.0663x over previous
//
#include <hip/hip_runtime.h>
#include <stdint.h>

typedef unsigned short u16;
typedef __attribute__((ext_vector_type(8))) __bf16 bf16x8;
typedef __attribute__((ext_vector_type(4))) float f32x4;

#define B_TOTAL 65536
#define KPAD1   1440   // 1424 padded to multiple of 32

__device__ __forceinline__ u16 f2bf(float f) {
  union { float f; uint32_t u; } v; v.f = f;
  uint32_t r = v.u + 0x7fffu + ((v.u >> 16) & 1u);
  return (u16)(r >> 16);
}
__device__ __forceinline__ float bf2f(u16 h) {
  union { uint32_t u; float f; } v; v.u = ((uint32_t)h) << 16;
  return v.f;
}

__device__ __forceinline__ void gload16(const void* g, void* lds) {
  __builtin_amdgcn_global_load_lds(
      (const __attribute__((address_space(1))) uint32_t*)g,
      (__attribute__((address_space(3))) uint32_t*)lds, 16, 0, 0);
}

// ---------------- weight prep: f32 [K][N] -> bf16 [N][Kpad] (transposed, zero-padded K)
__global__ void wprep_kernel(const float* __restrict__ W, u16* __restrict__ Wt,
                             int K, int N, int Kpad) {
  int o = blockIdx.x * 256 + threadIdx.x;
  if (o >= N * Kpad) return;
  int k = o % Kpad;
  int n = o / Kpad;
  float v = (k < K) ? W[(size_t)k * N + n] : 0.0f;
  Wt[o] = f2bf(v);
}

// ---------------- gather + concat -> X bf16 [Bc][1440]
struct GatherArgs {
  const int*   idx[15];
  const float* E[15];
  const int*   idx_u;
  const float* E_u;
};

constexpr int FDIM[15] = {128,128,128,16,16,96,144,64,80,64,48,144,96,16,144};
constexpr int FOFF[15] = {0,128,256,384,400,416,512,656,720,800,864,912,1056,1152,1168};

__global__ void gather_kernel(GatherArgs p, u16* __restrict__ X, int row_base) {
  const int lane = threadIdx.x & 63;
  const int row  = blockIdx.x * 4 + (threadIdx.x >> 6);
  const int grow = row_base + row;
  u16* xrow = X + (size_t)row * KPAD1;

#pragma unroll
  for (int f = 0; f < 15; ++f) {
    const int id = p.idx[f][grow];
    const float* src = p.E[f] + (size_t)id * FDIM[f];
    const int ng = FDIM[f] / 4;
    if (lane < ng) {
      const float4 v = *reinterpret_cast<const float4*>(src + lane * 4);
      ushort4 o;
      o.x = f2bf(v.x); o.y = f2bf(v.y); o.z = f2bf(v.z); o.w = f2bf(v.w);
      *reinterpret_cast<ushort4*>(xrow + FOFF[f] + lane * 4) = o;
    }
  }
  const int* iu = p.idx_u + (size_t)grow * 50;
  if (lane < 56) {
    float sx = 0.f, sy = 0.f;
    for (int j = 0; j < 50; ++j) {
      const int id = iu[j];
      const float2 v = *reinterpret_cast<const float2*>(p.E_u + (size_t)id * 112 + lane * 2);
      sx += v.x; sy += v.y;
    }
    const float inv = 1.0f / 50.0f;
    ushort2 o; o.x = f2bf(sx * inv); o.y = f2bf(sy * inv);
    *reinterpret_cast<ushort2*>(xrow + 1312 + lane * 2) = o;
  } else if (lane < 60) {
    ushort4 z; z.x = 0; z.y = 0; z.z = 0; z.w = 0;
    *reinterpret_cast<ushort4*>(xrow + 1424 + (lane - 56) * 4) = z;
  }
}

// ---------------- gemm8: 256x256 tile, BK=32, 3-buffer deep pipeline, swizzled LDS
// C[M][N] = relu(A[M][K] * Wt[N][K]^T + bias), bf16 out.
// LDS swizzle (involution): physical 16B-slot = logical_slot ^ ((row>>1)&3).
// Staging: linear LDS dest (global_load_lds) + inverse-swizzled global source.
#define TILE_ELE 16384   // u16 elems per buffer (A 8192 + B 8192)

__global__ __launch_bounds__(512, 2) void gemm8(
    const u16* __restrict__ A, const u16* __restrict__ Wt,
    const float* __restrict__ bias, u16* __restrict__ C,
    int M, int N, int K, int gm) {
  extern __shared__ __align__(16) u16 lds[];
  const int tid  = threadIdx.x;
  const int w    = tid >> 6;
  const int lane = tid & 63;
  const int fr   = lane & 15;
  const int kg   = lane >> 4;
  const int wm   = w >> 2;      // 0..1
  const int wn   = w & 3;       // 0..3

  // bijective XCD swizzle (m204), M-major so an XCD chunk shares the weight panel
  const int nwg = gridDim.x;
  const int q = nwg >> 3, r = nwg & 7;
  const int xcd = blockIdx.x & 7, lid = blockIdx.x >> 3;
  const int swz = (xcd < r) ? (xcd * (q + 1) + lid) : (r * (q + 1) + (xcd - r) * q + lid);
  const int bm = swz % gm, bn = swz / gm;
  const int rowBase = bm * 256, colBase = bn * 256;

  // staging: thread i = w*64+lane covers LDS bytes i*16 of a 4096-elem half-tile
  // linear LDS -> logical (row, slot): row = i>>2, physical slot = i&3
  // logical slot fetched from global = (i&3) ^ ((row>>1)&3) = (lane&3) ^ ((lane>>3)&3)
  const int srow  = lane >> 2;
  const int sslot = (lane & 3) ^ ((lane >> 3) & 3);
  const u16* Asrc0 = A  + (size_t)(rowBase + w * 16 + srow) * K + sslot * 8;
  const u16* Bsrc0 = Wt + (size_t)(colBase + w * 16 + srow) * K + sslot * 8;
  const size_t rstep = (size_t)128 * K;

  const int NT = K / 32;

  f32x4 acc[8][4];
#pragma unroll
  for (int m = 0; m < 8; ++m)
#pragma unroll
    for (int n = 0; n < 4; ++n)
      acc[m][n] = f32x4{0.f, 0.f, 0.f, 0.f};

  // read-side swizzled fragment bases (elems): physical slot = kg ^ ((fr>>1)&3)
  const int aslot8 = (kg ^ ((fr >> 1) & 3)) * 8;
  const int ardA = (wm * 128 + fr) * 32 + aslot8;          // + m*16*32 (+2048 for half 1) + buf
  const int ardB = (wn * 64 + fr) * 32 + aslot8 + 8192;    // + n*16*32 + buf

  auto stage = [&](const u16* src0, int ldsElemBase, int kt) {
    const u16* s = src0 + (size_t)kt * 32;
    gload16(s,         &lds[ldsElemBase + w * 512]);
    gload16(s + rstep, &lds[ldsElemBase + w * 512 + 4096]);
  };

  // prologue: stage tiles 0 and 1 (8 VMEM ops in flight per thread)
  stage(Asrc0, 0 * TILE_ELE,        0);
  stage(Bsrc0, 0 * TILE_ELE + 8192, 0);
  stage(Asrc0, 1 * TILE_ELE,        1);
  stage(Bsrc0, 1 * TILE_ELE + 8192, 1);

  for (int t = 0; t < NT; ++t) {
    const int cb = t % 3;
    const int sb = (t + 2) % 3;
    const bool dost = (t + 2) < NT;
    const int cA = cb * TILE_ELE;

    // tile boundary: ensure tile t's 4 halves landed; keep next tile's in flight
    if (t < NT - 1) asm volatile("s_waitcnt vmcnt(4)" ::: "memory");
    else            asm volatile("s_waitcnt vmcnt(0)" ::: "memory");
    __builtin_amdgcn_s_barrier();

    // ---------- phase 0: m-half 0 (+ all B frags) ----------
    bf16x8 a0 = *(const bf16x8*)&lds[cA + ardA + 0 * 512];
    bf16x8 a1 = *(const bf16x8*)&lds[cA + ardA + 1 * 512];
    bf16x8 a2 = *(const bf16x8*)&lds[cA + ardA + 2 * 512];
    bf16x8 a3 = *(const bf16x8*)&lds[cA + ardA + 3 * 512];
    bf16x8 b0 = *(const bf16x8*)&lds[cA + ardB + 0 * 512];
    bf16x8 b1 = *(const bf16x8*)&lds[cA + ardB + 1 * 512];
    bf16x8 b2 = *(const bf16x8*)&lds[cA + ardB + 2 * 512];
    bf16x8 b3 = *(const bf16x8*)&lds[cA + ardB + 3 * 512];
    if (dost) stage(Asrc0, sb * TILE_ELE, t + 2);
    __builtin_amdgcn_s_barrier();
    asm volatile("s_waitcnt lgkmcnt(0)" ::: "memory");
    __builtin_amdgcn_sched_barrier(0);
    __builtin_amdgcn_s_setprio(1);
    acc[0][0] = __builtin_amdgcn_mfma_f32_16x16x32_bf16(a0, b0, acc[0][0], 0, 0, 0);
    acc[0][1] = __builtin_amdgcn_mfma_f32_16x16x32_bf16(a0, b1, acc[0][1], 0, 0, 0);
    acc[0][2] = __builtin_amdgcn_mfma_f32_16x16x32_bf16(a0, b2, acc[0][2], 0, 0, 0);
    acc[0][3] = __builtin_amdgcn_mfma_f32_16x16x32_bf16(a0, b3, acc[0][3], 0, 0, 0);
    acc[1][0] = __builtin_amdgcn_mfma_f32_16x16x32_bf16(a1, b0, acc[1][0], 0, 0, 0);
    acc[1][1] = __builtin_amdgcn_mfma_f32_16x16x32_bf16(a1, b1, acc[1][1], 0, 0, 0);
    acc[1][2] = __builtin_amdgcn_mfma_f32_16x16x32_bf16(a1, b2, acc[1][2], 0, 0, 0);
    acc[1][3] = __builtin_amdgcn_mfma_f32_16x16x32_bf16(a1, b3, acc[1][3], 0, 0, 0);
    acc[2][0] = __builtin_amdgcn_mfma_f32_16x16x32_bf16(a2, b0, acc[2][0], 0, 0, 0);
    acc[2][1] = __builtin_amdgcn_mfma_f32_16x16x32_bf16(a2, b1, acc[2][1], 0, 0, 0);
    acc[2][2] = __builtin_amdgcn_mfma_f32_16x16x32_bf16(a2, b2, acc[2][2], 0, 0, 0);
    acc[2][3] = __builtin_amdgcn_mfma_f32_16x16x32_bf16(a2, b3, acc[2][3], 0, 0, 0);
    acc[3][0] = __builtin_amdgcn_mfma_f32_16x16x32_bf16(a3, b0, acc[3][0], 0, 0, 0);
    acc[3][1] = __builtin_amdgcn_mfma_f32_16x16x32_bf16(a3, b1, acc[3][1], 0, 0, 0);
    acc[3][2] = __builtin_amdgcn_mfma_f32_16x16x32_bf16(a3, b2, acc[3][2], 0, 0, 0);
    acc[3][3] = __builtin_amdgcn_mfma_f32_16x16x32_bf16(a3, b3, acc[3][3], 0, 0, 0);
    __builtin_amdgcn_s_setprio(0);
    __builtin_amdgcn_s_barrier();

    // ---------- phase 1: m-half 1 ----------
    bf16x8 c0 = *(const bf16x8*)&lds[cA + ardA + 2048 + 0 * 512];
    bf16x8 c1 = *(const bf16x8*)&lds[cA + ardA + 2048 + 1 * 512];
    bf16x8 c2 = *(const bf16x8*)&lds[cA + ardA + 2048 + 2 * 512];
    bf16x8 c3 = *(const bf16x8*)&lds[cA + ardA + 2048 + 3 * 512];
    if (dost) stage(Bsrc0, sb * TILE_ELE + 8192, t + 2);
    __builtin_amdgcn_s_barrier();
    asm volatile("s_waitcnt lgkmcnt(0)" ::: "memory");
    __builtin_amdgcn_sched_barrier(0);
    __builtin_amdgcn_s_setprio(1);
    acc[4][0] = __builtin_amdgcn_mfma_f32_16x16x32_bf16(c0, b0, acc[4][0], 0, 0, 0);
    acc[4][1] = __builtin_amdgcn_mfma_f32_16x16x32_bf16(c0, b1, acc[4][1], 0, 0, 0);
    acc[4][2] = __builtin_amdgcn_mfma_f32_16x16x32_bf16(c0, b2, acc[4][2], 0, 0, 0);
    acc[4][3] = __builtin_amdgcn_mfma_f32_16x16x32_bf16(c0, b3, acc[4][3], 0, 0, 0);
    acc[5][0] = __builtin_amdgcn_mfma_f32_16x16x32_bf16(c1, b0, acc[5][0], 0, 0, 0);
    acc[5][1] = __builtin_amdgcn_mfma_f32_16x16x32_bf16(c1, b1, acc[5][1], 0, 0, 0);
    acc[5][2] = __builtin_amdgcn_mfma_f32_16x16x32_bf16(c1, b2, acc[5][2], 0, 0, 0);
    acc[5][3] = __builtin_amdgcn_mfma_f32_16x16x32_bf16(c1, b3, acc[5][3], 0, 0, 0);
    acc[6][0] = __builtin_amdgcn_mfma_f32_16x16x32_bf16(c2, b0, acc[6][0], 0, 0, 0);
    acc[6][1] = __builtin_amdgcn_mfma_f32_16x16x32_bf16(c2, b1, acc[6][1], 0, 0, 0);
    acc[6][2] = __builtin_amdgcn_mfma_f32_16x16x32_bf16(c2, b2, acc[6][2], 0, 0, 0);
    acc[6][3] = __builtin_amdgcn_mfma_f32_16x16x32_bf16(c2, b3, acc[6][3], 0, 0, 0);
    acc[7][0] = __builtin_amdgcn_mfma_f32_16x16x32_bf16(c3, b0, acc[7][0], 0, 0, 0);
    acc[7][1] = __builtin_amdgcn_mfma_f32_16x16x32_bf16(c3, b1, acc[7][1], 0, 0, 0);
    acc[7][2] = __builtin_amdgcn_mfma_f32_16x16x32_bf16(c3, b2, acc[7][2], 0, 0, 0);
    acc[7][3] = __builtin_amdgcn_mfma_f32_16x16x32_bf16(c3, b3, acc[7][3], 0, 0, 0);
    __builtin_amdgcn_s_setprio(0);
  }

  // epilogue: bias + relu + bf16 store
#pragma unroll
  for (int n = 0; n < 4; ++n) {
    const int col = colBase + wn * 64 + n * 16 + fr;
    const float bv = bias[col];
#pragma unroll
    for (int mm = 0; mm < 8; ++mm) {
      const int row0 = rowBase + wm * 128 + (mm >> 2) * 64 + (mm & 3) * 16 + kg * 4;
#pragma unroll
      for (int j = 0; j < 4; ++j) {
        float v = acc[mm][n][j] + bv;
        v = fmaxf(v, 0.f);
        C[(size_t)(row0 + j) * N + col] = f2bf(v);
      }
    }
  }
}

// ---------------- final: h3[Bc][256] -> relu(h3*W4+b4) -> softmax(2) -> f32 out
__global__ void final_kernel(const u16* __restrict__ H3, const float* __restrict__ W4,
                             const float* __restrict__ b4, float* __restrict__ out, int M) {
  const int lane = threadIdx.x & 63;
  const int row  = blockIdx.x * 4 + (threadIdx.x >> 6);
  const ushort4 h = *reinterpret_cast<const ushort4*>(H3 + (size_t)row * 256 + lane * 4);
  const float x0 = bf2f(h.x), x1 = bf2f(h.y), x2 = bf2f(h.z), x3 = bf2f(h.w);
  const float2 w0 = *reinterpret_cast<const float2*>(W4 + (size_t)(lane * 4 + 0) * 2);
  const float2 w1 = *reinterpret_cast<const float2*>(W4 + (size_t)(lane * 4 + 1) * 2);
  const float2 w2 = *reinterpret_cast<const float2*>(W4 + (size_t)(lane * 4 + 2) * 2);
  const float2 w3 = *reinterpret_cast<const float2*>(W4 + (size_t)(lane * 4 + 3) * 2);
  float s0 = x0 * w0.x + x1 * w1.x + x2 * w2.x + x3 * w3.x;
  float s1 = x0 * w0.y + x1 * w1.y + x2 * w2.y + x3 * w3.y;
#pragma unroll
  for (int off = 32; off > 0; off >>= 1) {
    s0 += __shfl_xor(s0, off);
    s1 += __shfl_xor(s1, off);
  }
  if (lane == 0) {
    float z0 = fmaxf(s0 + b4[0], 0.f);
    float z1 = fmaxf(s1 + b4[1], 0.f);
    float mx = fmaxf(z0, z1);
    float e0 = __expf(z0 - mx), e1 = __expf(z1 - mx);
    float inv = 1.0f / (e0 + e1);
    out[(size_t)row * 2]     = e0 * inv;
    out[(size_t)row * 2 + 1] = e1 * inv;
  }
}

// ---------------- host side
extern "C" void kernel_launch(void* const* d_in, const int* in_sizes, int n_in,
                              void* d_out, int out_size, void* d_ws, size_t ws_size,
                              hipStream_t stream) {
  const float* W1 = (const float*)d_in[32];
  const float* b1 = (const float*)d_in[33];
  const float* W2 = (const float*)d_in[34];
  const float* b2 = (const float*)d_in[35];
  const float* W3 = (const float*)d_in[36];
  const float* b3 = (const float*)d_in[37];
  const float* W4 = (const float*)d_in[38];
  const float* b4 = (const float*)d_in[39];

  // host-side, non-stream, deterministic on every call (no static guards)
  (void)hipFuncSetAttribute(reinterpret_cast<const void*>(&gemm8),
                            hipFuncAttributeMaxDynamicSharedMemorySize, 98304);

  char* ws = (char*)d_ws;
  size_t off = 0;
  auto alloc = [&](size_t bytes) -> void* {
    void* p = ws + off;
    off += (bytes + 255) & ~(size_t)255;
    return p;
  };

  u16* W1t = (u16*)alloc((size_t)1024 * KPAD1 * 2);
  u16* W2t = (u16*)alloc((size_t)512 * 1024 * 2);
  u16* W3t = (u16*)alloc((size_t)256 * 512 * 2);
  const size_t fixed = off;

  int nc = 64;
  const int cands[7] = {1, 2, 4, 8, 16, 32, 64};
  for (int ci = 0; ci < 7; ++ci) {
    size_t Bc = (size_t)B_TOTAL / cands[ci];
    size_t need = fixed + Bc * (KPAD1 + 1024 + 512 + 256) * 2 + 4096;
    if (need <= ws_size) { nc = cands[ci]; break; }
  }
  const int Bc = B_TOTAL / nc;

  u16* X  = (u16*)alloc((size_t)Bc * KPAD1 * 2);
  u16* H1 = (u16*)alloc((size_t)Bc * 1024 * 2);
  u16* H2 = (u16*)alloc((size_t)Bc * 512 * 2);
  u16* H3 = (u16*)alloc((size_t)Bc * 256 * 2);

  wprep_kernel<<<(1024 * KPAD1 + 255) / 256, 256, 0, stream>>>(W1, W1t, 1424, 1024, KPAD1);
  wprep_kernel<<<(512 * 1024 + 255) / 256, 256, 0, stream>>>(W2, W2t, 1024, 512, 1024);
  wprep_kernel<<<(256 * 512 + 255) / 256, 256, 0, stream>>>(W3, W3t, 512, 256, 512);

  GatherArgs ga;
  for (int f = 0; f < 15; ++f) {
    ga.idx[f] = (const int*)d_in[2 * f];
    ga.E[f]   = (const float*)d_in[2 * f + 1];
  }
  ga.idx_u = (const int*)d_in[30];
  ga.E_u   = (const float*)d_in[31];

  const int gm = Bc / 256;
  for (int c = 0; c < nc; ++c) {
    gather_kernel<<<Bc / 4, 256, 0, stream>>>(ga, X, c * Bc);
    gemm8<<<gm * (1024 / 256), 512, 98304, stream>>>(X, W1t, b1, H1, Bc, 1024, KPAD1, gm);
    gemm8<<<gm * (512 / 256), 512, 98304, stream>>>(H1, W2t, b2, H2, Bc, 512, 1024, gm);
    gemm8<<<gm * (256 / 256), 512, 98304, stream>>>(H2, W3t, b3, H3, Bc, 256, 512, gm);
    final_kernel<<<Bc / 4, 256, 0, stream>>>(H3, W4, b4, (float*)d_out + (size_t)c * Bc * 2, Bc);
  }
}

// Round 8
// 552.297 us; speedup vs baseline: 1.0714x; 1.0048x over previous
//
#include <hip/hip_runtime.h>
#include <stdint.h>

typedef unsigned short u16;
typedef __attribute__((ext_vector_type(8))) __bf16 bf16x8;
typedef __attribute__((ext_vector_type(4))) float f32x4;

#define B_TOTAL 65536
#define KPAD1   1440   // 1424 padded to multiple of 32

__device__ __forceinline__ u16 f2bf(float f) {
  union { float f; uint32_t u; } v; v.f = f;
  uint32_t r = v.u + 0x7fffu + ((v.u >> 16) & 1u);
  return (u16)(r >> 16);
}
__device__ __forceinline__ float bf2f(u16 h) {
  union { uint32_t u; float f; } v; v.u = ((uint32_t)h) << 16;
  return v.f;
}

__device__ __forceinline__ void gload16(const void* g, void* lds) {
  __builtin_amdgcn_global_load_lds(
      (const __attribute__((address_space(1))) uint32_t*)g,
      (__attribute__((address_space(3))) uint32_t*)lds, 16, 0, 0);
}

// ---------------- weight prep: f32 [K][N] -> bf16 [N][Kpad] (transposed, zero-padded K)
__global__ void wprep_kernel(const float* __restrict__ W, u16* __restrict__ Wt,
                             int K, int N, int Kpad) {
  int o = blockIdx.x * 256 + threadIdx.x;
  if (o >= N * Kpad) return;
  int k = o % Kpad;
  int n = o / Kpad;
  float v = (k < K) ? W[(size_t)k * N + n] : 0.0f;
  Wt[o] = f2bf(v);
}

// ---------------- gather + concat -> X bf16 [Bc][1440]
struct GatherArgs {
  const int*   idx[15];
  const float* E[15];
  const int*   idx_u;
  const float* E_u;
};

constexpr int FDIM[15] = {128,128,128,16,16,96,144,64,80,64,48,144,96,16,144};
constexpr int FOFF[15] = {0,128,256,384,400,416,512,656,720,800,864,912,1056,1152,1168};

__global__ void gather_kernel(GatherArgs p, u16* __restrict__ X, int row_base) {
  const int lane = threadIdx.x & 63;
  const int row  = blockIdx.x * 4 + (threadIdx.x >> 6);
  const int grow = row_base + row;
  u16* xrow = X + (size_t)row * KPAD1;

#pragma unroll
  for (int f = 0; f < 15; ++f) {
    const int id = p.idx[f][grow];
    const float* src = p.E[f] + (size_t)id * FDIM[f];
    const int ng = FDIM[f] / 4;
    if (lane < ng) {
      const float4 v = *reinterpret_cast<const float4*>(src + lane * 4);
      ushort4 o;
      o.x = f2bf(v.x); o.y = f2bf(v.y); o.z = f2bf(v.z); o.w = f2bf(v.w);
      *reinterpret_cast<ushort4*>(xrow + FOFF[f] + lane * 4) = o;
    }
  }
  // userids mean-pool over 50, dim 112: lanes 0..27 take 4 cols each, 2-deep ILP
  const int* iu = p.idx_u + (size_t)grow * 50;
  if (lane < 28) {
    float4 s0 = {0.f, 0.f, 0.f, 0.f}, s1 = {0.f, 0.f, 0.f, 0.f};
#pragma unroll 5
    for (int j = 0; j < 50; j += 2) {
      const int i0 = iu[j];
      const int i1 = iu[j + 1];
      const float4 v0 = *reinterpret_cast<const float4*>(p.E_u + (size_t)i0 * 112 + lane * 4);
      const float4 v1 = *reinterpret_cast<const float4*>(p.E_u + (size_t)i1 * 112 + lane * 4);
      s0.x += v0.x; s0.y += v0.y; s0.z += v0.z; s0.w += v0.w;
      s1.x += v1.x; s1.y += v1.y; s1.z += v1.z; s1.w += v1.w;
    }
    const float inv = 1.0f / 50.0f;
    ushort4 o;
    o.x = f2bf((s0.x + s1.x) * inv);
    o.y = f2bf((s0.y + s1.y) * inv);
    o.z = f2bf((s0.z + s1.z) * inv);
    o.w = f2bf((s0.w + s1.w) * inv);
    *reinterpret_cast<ushort4*>(xrow + 1312 + lane * 4) = o;
  } else if (lane < 32) {
    ushort4 z; z.x = 0; z.y = 0; z.z = 0; z.w = 0;
    *reinterpret_cast<ushort4*>(xrow + 1424 + (lane - 28) * 4) = z;
  }
}

// ---------------- gemm8: 256x256 tile, BK=32, 3-buffer pipeline, swizzled LDS, free-run
// C[M][N] = relu(A[M][K] * Wt[N][K]^T + bias), bf16 out.
// LDS swizzle (involution): physical 16B-slot = logical_slot ^ ((row>>1)&3).
// Staging: linear LDS dest (global_load_lds) + inverse-swizzled global source.
// One barrier + counted vmcnt per K-tile; waves free-run inside the tile so
// one wave's ds_reads overlap another's MFMAs (compiler emits fine lgkmcnt).
#define TILE_ELE 16384   // u16 elems per buffer (A 8192 + B 8192)

__global__ __launch_bounds__(512, 2) void gemm8(
    const u16* __restrict__ A, const u16* __restrict__ Wt,
    const float* __restrict__ bias, u16* __restrict__ C,
    int M, int N, int K, int gm) {
  extern __shared__ __align__(16) u16 lds[];
  const int tid  = threadIdx.x;
  const int w    = tid >> 6;
  const int lane = tid & 63;
  const int fr   = lane & 15;
  const int kg   = lane >> 4;
  const int wm   = w >> 2;      // 0..1
  const int wn   = w & 3;       // 0..3

  // bijective XCD swizzle (m204), M-major so an XCD chunk shares the weight panel
  const int nwg = gridDim.x;
  const int q = nwg >> 3, r = nwg & 7;
  const int xcd = blockIdx.x & 7, lid = blockIdx.x >> 3;
  const int swz = (xcd < r) ? (xcd * (q + 1) + lid) : (r * (q + 1) + (xcd - r) * q + lid);
  const int bm = swz % gm, bn = swz / gm;
  const int rowBase = bm * 256, colBase = bn * 256;

  // staging: thread i = w*64+lane covers LDS bytes i*16 of a 4096-elem half-tile
  // logical slot fetched from global = (lane&3) ^ ((lane>>3)&3)
  const int srow  = lane >> 2;
  const int sslot = (lane & 3) ^ ((lane >> 3) & 3);
  const u16* Asrc0 = A  + (size_t)(rowBase + w * 16 + srow) * K + sslot * 8;
  const u16* Bsrc0 = Wt + (size_t)(colBase + w * 16 + srow) * K + sslot * 8;
  const size_t rstep = (size_t)128 * K;

  const int NT = K / 32;

  f32x4 acc[8][4];
#pragma unroll
  for (int m = 0; m < 8; ++m)
#pragma unroll
    for (int n = 0; n < 4; ++n)
      acc[m][n] = f32x4{0.f, 0.f, 0.f, 0.f};

  // read-side swizzled fragment bases (elems): physical slot = kg ^ ((fr>>1)&3)
  const int aslot8 = (kg ^ ((fr >> 1) & 3)) * 8;
  const int ardA = (wm * 128 + fr) * 32 + aslot8;          // + m*16*32 (+2048 for half 1) + buf
  const int ardB = (wn * 64 + fr) * 32 + aslot8 + 8192;    // + n*16*32 + buf

  auto stage = [&](const u16* src0, int ldsElemBase, int kt) {
    const u16* s = src0 + (size_t)kt * 32;
    gload16(s,         &lds[ldsElemBase + w * 512]);
    gload16(s + rstep, &lds[ldsElemBase + w * 512 + 4096]);
  };

  // prologue: stage tiles 0 and 1 (8 VMEM ops in flight per thread)
  stage(Asrc0, 0 * TILE_ELE,        0);
  stage(Bsrc0, 0 * TILE_ELE + 8192, 0);
  stage(Asrc0, 1 * TILE_ELE,        1);
  stage(Bsrc0, 1 * TILE_ELE + 8192, 1);

  for (int t = 0; t < NT; ++t) {
    const int cb = t % 3;
    const int sb = (t + 2) % 3;
    const bool dost = (t + 2) < NT;
    const int cA = cb * TILE_ELE;

    // tile boundary: tile t's 4 stage ops landed; next tile's stay in flight.
    // A wave's tile-(t-1) ds_reads were drained before its MFMAs issued, so
    // after this barrier nobody can still be reading buffer (t+2)%3 == (t-1)%3.
    __builtin_amdgcn_sched_barrier(0);
    if (t < NT - 1) asm volatile("s_waitcnt vmcnt(4)" ::: "memory");
    else            asm volatile("s_waitcnt vmcnt(0)" ::: "memory");
    __builtin_amdgcn_s_barrier();
    __builtin_amdgcn_sched_barrier(0);

    // free-run: 12 ds_reads + stage of tile t+2 + 32 MFMAs, compiler-scheduled
    bf16x8 a0 = *(const bf16x8*)&lds[cA + ardA + 0 * 512];
    bf16x8 a1 = *(const bf16x8*)&lds[cA + ardA + 1 * 512];
    bf16x8 a2 = *(const bf16x8*)&lds[cA + ardA + 2 * 512];
    bf16x8 a3 = *(const bf16x8*)&lds[cA + ardA + 3 * 512];
    bf16x8 b0 = *(const bf16x8*)&lds[cA + ardB + 0 * 512];
    bf16x8 b1 = *(const bf16x8*)&lds[cA + ardB + 1 * 512];
    bf16x8 b2 = *(const bf16x8*)&lds[cA + ardB + 2 * 512];
    bf16x8 b3 = *(const bf16x8*)&lds[cA + ardB + 3 * 512];
    bf16x8 c0 = *(const bf16x8*)&lds[cA + ardA + 2048 + 0 * 512];
    bf16x8 c1 = *(const bf16x8*)&lds[cA + ardA + 2048 + 1 * 512];
    bf16x8 c2 = *(const bf16x8*)&lds[cA + ardA + 2048 + 2 * 512];
    bf16x8 c3 = *(const bf16x8*)&lds[cA + ardA + 2048 + 3 * 512];
    if (dost) {
      stage(Asrc0, sb * TILE_ELE,        t + 2);
      stage(Bsrc0, sb * TILE_ELE + 8192, t + 2);
    }
    // operand-swapped MFMA: D^T orientation -> lane's 4 acc elems are 4
    // consecutive output COLUMNS (enables packed 8B stores in the epilogue)
#pragma unroll
    for (int n = 0; n < 4; ++n) {
      bf16x8 bf = (n == 0) ? b0 : (n == 1) ? b1 : (n == 2) ? b2 : b3;
      acc[0][n] = __builtin_amdgcn_mfma_f32_16x16x32_bf16(bf, a0, acc[0][n], 0, 0, 0);
      acc[1][n] = __builtin_amdgcn_mfma_f32_16x16x32_bf16(bf, a1, acc[1][n], 0, 0, 0);
      acc[2][n] = __builtin_amdgcn_mfma_f32_16x16x32_bf16(bf, a2, acc[2][n], 0, 0, 0);
      acc[3][n] = __builtin_amdgcn_mfma_f32_16x16x32_bf16(bf, a3, acc[3][n], 0, 0, 0);
      acc[4][n] = __builtin_amdgcn_mfma_f32_16x16x32_bf16(bf, c0, acc[4][n], 0, 0, 0);
      acc[5][n] = __builtin_amdgcn_mfma_f32_16x16x32_bf16(bf, c1, acc[5][n], 0, 0, 0);
      acc[6][n] = __builtin_amdgcn_mfma_f32_16x16x32_bf16(bf, c2, acc[6][n], 0, 0, 0);
      acc[7][n] = __builtin_amdgcn_mfma_f32_16x16x32_bf16(bf, c3, acc[7][n], 0, 0, 0);
    }
  }

  // epilogue: bias + relu + packed bf16x4 (8B) stores.
  // D^T layout: lane&15 (fr) = m-local row of the m-tile; (lane>>4)*4+j (kg*4+j)
  // = n-local col of the n-tile -> regs j are 4 consecutive columns.
#pragma unroll
  for (int mm = 0; mm < 8; ++mm) {
    const int row = rowBase + wm * 128 + (mm >> 2) * 64 + (mm & 3) * 16 + fr;
#pragma unroll
    for (int n = 0; n < 4; ++n) {
      const int col0 = colBase + wn * 64 + n * 16 + kg * 4;
      ushort4 o;
      o.x = f2bf(fmaxf(acc[mm][n][0] + bias[col0 + 0], 0.f));
      o.y = f2bf(fmaxf(acc[mm][n][1] + bias[col0 + 1], 0.f));
      o.z = f2bf(fmaxf(acc[mm][n][2] + bias[col0 + 2], 0.f));
      o.w = f2bf(fmaxf(acc[mm][n][3] + bias[col0 + 3], 0.f));
      *reinterpret_cast<ushort4*>(&C[(size_t)row * N + col0]) = o;
    }
  }
}

// ---------------- final: h3[Bc][256] -> relu(h3*W4+b4) -> softmax(2) -> f32 out
__global__ void final_kernel(const u16* __restrict__ H3, const float* __restrict__ W4,
                             const float* __restrict__ b4, float* __restrict__ out, int M) {
  const int lane = threadIdx.x & 63;
  const int row  = blockIdx.x * 4 + (threadIdx.x >> 6);
  const ushort4 h = *reinterpret_cast<const ushort4*>(H3 + (size_t)row * 256 + lane * 4);
  const float x0 = bf2f(h.x), x1 = bf2f(h.y), x2 = bf2f(h.z), x3 = bf2f(h.w);
  const float2 w0 = *reinterpret_cast<const float2*>(W4 + (size_t)(lane * 4 + 0) * 2);
  const float2 w1 = *reinterpret_cast<const float2*>(W4 + (size_t)(lane * 4 + 1) * 2);
  const float2 w2 = *reinterpret_cast<const float2*>(W4 + (size_t)(lane * 4 + 2) * 2);
  const float2 w3 = *reinterpret_cast<const float2*>(W4 + (size_t)(lane * 4 + 3) * 2);
  float s0 = x0 * w0.x + x1 * w1.x + x2 * w2.x + x3 * w3.x;
  float s1 = x0 * w0.y + x1 * w1.y + x2 * w2.y + x3 * w3.y;
#pragma unroll
  for (int off = 32; off > 0; off >>= 1) {
    s0 += __shfl_xor(s0, off);
    s1 += __shfl_xor(s1, off);
  }
  if (lane == 0) {
    float z0 = fmaxf(s0 + b4[0], 0.f);
    float z1 = fmaxf(s1 + b4[1], 0.f);
    float mx = fmaxf(z0, z1);
    float e0 = __expf(z0 - mx), e1 = __expf(z1 - mx);
    float inv = 1.0f / (e0 + e1);
    out[(size_t)row * 2]     = e0 * inv;
    out[(size_t)row * 2 + 1] = e1 * inv;
  }
}

// ---------------- host side
extern "C" void kernel_launch(void* const* d_in, const int* in_sizes, int n_in,
                              void* d_out, int out_size, void* d_ws, size_t ws_size,
                              hipStream_t stream) {
  const float* W1 = (const float*)d_in[32];
  const float* b1 = (const float*)d_in[33];
  const float* W2 = (const float*)d_in[34];
  const float* b2 = (const float*)d_in[35];
  const float* W3 = (const float*)d_in[36];
  const float* b3 = (const float*)d_in[37];
  const float* W4 = (const float*)d_in[38];
  const float* b4 = (const float*)d_in[39];

  // host-side, non-stream, deterministic on every call
  (void)hipFuncSetAttribute(reinterpret_cast<const void*>(&gemm8),
                            hipFuncAttributeMaxDynamicSharedMemorySize, 98304);

  char* ws = (char*)d_ws;
  size_t off = 0;
  auto alloc = [&](size_t bytes) -> void* {
    void* p = ws + off;
    off += (bytes + 255) & ~(size_t)255;
    return p;
  };

  u16* W1t = (u16*)alloc((size_t)1024 * KPAD1 * 2);
  u16* W2t = (u16*)alloc((size_t)512 * 1024 * 2);
  u16* W3t = (u16*)alloc((size_t)256 * 512 * 2);
  const size_t fixed = off;

  int nc = 64;
  const int cands[7] = {1, 2, 4, 8, 16, 32, 64};
  for (int ci = 0; ci < 7; ++ci) {
    size_t Bc = (size_t)B_TOTAL / cands[ci];
    size_t need = fixed + Bc * (KPAD1 + 1024 + 512 + 256) * 2 + 4096;
    if (need <= ws_size) { nc = cands[ci]; break; }
  }
  const int Bc = B_TOTAL / nc;

  u16* X  = (u16*)alloc((size_t)Bc * KPAD1 * 2);
  u16* H1 = (u16*)alloc((size_t)Bc * 1024 * 2);
  u16* H2 = (u16*)alloc((size_t)Bc * 512 * 2);
  u16* H3 = (u16*)alloc((size_t)Bc * 256 * 2);

  wprep_kernel<<<(1024 * KPAD1 + 255) / 256, 256, 0, stream>>>(W1, W1t, 1424, 1024, KPAD1);
  wprep_kernel<<<(512 * 1024 + 255) / 256, 256, 0, stream>>>(W2, W2t, 1024, 512, 1024);
  wprep_kernel<<<(256 * 512 + 255) / 256, 256, 0, stream>>>(W3, W3t, 512, 256, 512);

  GatherArgs ga;
  for (int f = 0; f < 15; ++f) {
    ga.idx[f] = (const int*)d_in[2 * f];
    ga.E[f]   = (const float*)d_in[2 * f + 1];
  }
  ga.idx_u = (const int*)d_in[30];
  ga.E_u   = (const float*)d_in[31];

  const int gm = Bc / 256;
  for (int c = 0; c < nc; ++c) {
    gather_kernel<<<Bc / 4, 256, 0, stream>>>(ga, X, c * Bc);
    gemm8<<<gm * (1024 / 256), 512, 98304, stream>>>(X, W1t, b1, H1, Bc, 1024, KPAD1, gm);
    gemm8<<<gm * (512 / 256), 512, 98304, stream>>>(H1, W2t, b2, H2, Bc, 512, 1024, gm);
    gemm8<<<gm * (256 / 256), 512, 98304, stream>>>(H2, W3t, b3, H3, Bc, 256, 512, gm);
    final_kernel<<<Bc / 4, 256, 0, stream>>>(H3, W4, b4, (float*)d_out + (size_t)c * Bc * 2, Bc);
  }
}